// Round 8
// baseline (74.115 us; speedup 1.0000x reference)
//
#include <hip/hip_runtime.h>

// out[b, c, vox] = valid[vox] ? feat[b, cam[vox], c, v[vox], u[vox]] : 0
// feat: (B=4, N=6, C=64, H=64, W=176) f32; out: (B=4, C=64, 240000) f32
//
// P1 transpose feat -> ws (B, N*H*W, C) bf16 channel-last (cache-allocating
//    stores; nt loads on feat).
// P2 gather: one block = one 64-voxel tile x one batch-PAIR. po_s computed
//    once, reused for both batches. XCD-quad pinning: batch-pair p -> XCDs
//    {4p..4p+3}; ws working set 17.3 MB over 4 L2s. Bijective tile map.

constexpr int NB   = 4;
constexpr int NCAM = 6;
constexpr int NC   = 64;
constexpr int NH   = 64;
constexpr int NW   = 176;
constexpr int NVOX = 240000;
constexpr int HW   = NH * NW;        // 11264
constexpr int CHW  = NC * HW;        // 720896
constexpr int NPIX = NCAM * HW;      // 67584 pixels per batch

constexpr int TILES_B  = NVOX / 64;              // 3750 voxel-tiles per batch
constexpr int KPX      = (TILES_B + 3) / 4;      // 938 tiles per XCD in a quad
constexpr int GBLOCKS  = 8 * KPX;                // 7504 (2 per bp exit early)

constexpr size_t WS_NEEDED = (size_t)NB * NPIX * NC * 2;   // 34,603,008

typedef float        f32x4 __attribute__((ext_vector_type(4)));
typedef unsigned int u32x4 __attribute__((ext_vector_type(4)));

__device__ __forceinline__ unsigned short f32_to_bf16_rne(float f) {
    unsigned int u = __float_as_uint(f);
    u += 0x7FFFu + ((u >> 16) & 1u);      // round to nearest even
    return (unsigned short)(u >> 16);
}

// ---------- P1: transpose feat (b,n,C,HW) f32 -> ws (b, n*HW+pix, C) bf16 ----
__global__ __launch_bounds__(256) void transpose_kernel(
    const float* __restrict__ feat, unsigned short* __restrict__ wst)
{
    __shared__ unsigned short lds[64][66];
    const int bid  = blockIdx.x;
    const int tile = bid % (HW / 64);        // 176 tiles
    const int bn   = bid / (HW / 64);        // b*6+n
    const int px0  = tile * 64;
    const int t    = threadIdx.x;

    const float* src = feat + (size_t)bn * CHW + px0;
#pragma unroll
    for (int r = 0; r < 16; ++r) {
        const int c  = r * 4 + (t >> 6);
        const int px = t & 63;
        const float f = __builtin_nontemporal_load(&src[(size_t)c * HW + px]);
        lds[px][c] = f32_to_bf16_rne(f);
    }
    __syncthreads();

    unsigned short* dst = wst + ((size_t)bn * HW + px0) * NC;
#pragma unroll
    for (int j = 0; j < 2; ++j) {
        const int px    = t >> 2;
        const int chunk = (t & 3) + 4 * j;    // 8-channel chunk
        u32x4 o;
#pragma unroll
        for (int p = 0; p < 4; ++p) {
            const unsigned int lo = lds[px][chunk * 8 + 2 * p];
            const unsigned int hi = lds[px][chunk * 8 + 2 * p + 1];
            o[p] = lo | (hi << 16);
        }
        *reinterpret_cast<u32x4*>(dst + (size_t)px * NC + chunk * 8) = o;
    }
}

// ---------- P2: gather, one block = (batch-pair, 64-voxel tile) ----------
__global__ __launch_bounds__(256) void gather_cl_kernel(
    const unsigned short* __restrict__ wst,
    const int* __restrict__ cam, const int* __restrict__ uu,
    const int* __restrict__ vv,  const int* __restrict__ valid,
    float* __restrict__ out)
{
    __shared__ float ot[64][65];             // [ch][vox]
    __shared__ int   po_s[64];

    // XCD-quad swizzle: xcd = bid%8 heuristic; batch-pair bp = xcd>>2.
    const int xcd  = blockIdx.x & 7;
    const int bp   = xcd >> 2;               // 0: b in {0,1}; 1: b in {2,3}
    const int q    = xcd & 3;
    const int k    = blockIdx.x >> 3;        // [0, 938)
    const int tile = q * KPX + k;
    if (tile >= TILES_B) return;             // uniform per-block exit
    const int vox0 = tile * 64;
    const int t    = threadIdx.x;

    if (t < 64) {
        const int i = vox0 + t;
        po_s[t] = valid[i] ? cam[i] * HW + vv[i] * NW + uu[i] : -1;
    }
    __syncthreads();

    const int vox = (t >> 3) & 31;           // reused below via r offset
#pragma unroll
    for (int bb = 0; bb < 2; ++bb) {
        const int b = 2 * bp + bb;
        const unsigned short* wb = wst + (size_t)b * NPIX * NC;

#pragma unroll
        for (int r = 0; r < 2; ++r) {
            const int vx  = r * 32 + (t >> 3);
            const int kk  = t & 7;           // channel octet
            const int pix = po_s[vx];
            if (pix >= 0) {
                const u32x4 raw = *reinterpret_cast<const u32x4*>(
                    wb + (size_t)pix * NC + kk * 8);
#pragma unroll
                for (int p = 0; p < 4; ++p) {
                    ot[kk * 8 + 2 * p][vx]     = __uint_as_float(raw[p] << 16);
                    ot[kk * 8 + 2 * p + 1][vx] = __uint_as_float(raw[p] & 0xFFFF0000u);
                }
            } else {
#pragma unroll
                for (int e = 0; e < 8; ++e) ot[kk * 8 + e][vx] = 0.0f;
            }
        }
        __syncthreads();

        float* ob = out + (size_t)b * NC * NVOX + vox0;
#pragma unroll
        for (int i = 0; i < 4; ++i) {
            const int slot = i * 256 + t;
            const int ch   = slot >> 4;      // 4 ch per wave
            const int g    = slot & 15;      // 4-voxel group
            f32x4 val = { ot[ch][4 * g], ot[ch][4 * g + 1],
                          ot[ch][4 * g + 2], ot[ch][4 * g + 3] };
            __builtin_nontemporal_store(val,
                reinterpret_cast<f32x4*>(ob + (size_t)ch * NVOX + 4 * g));
        }
        if (bb == 0) __syncthreads();        // protect ot before refill
    }
    (void)vox;
}

// ---------- fallback if ws too small ----------
__global__ __launch_bounds__(256) void gather_direct_kernel(
    const float* __restrict__ feat,
    const int* __restrict__ cam, const int* __restrict__ u,
    const int* __restrict__ v,   const int* __restrict__ valid,
    float* __restrict__ out)
{
    const int NG = NVOX / 4;
    const int t  = blockIdx.x * 256 + threadIdx.x;
    const int g  = t % NG;
    const int bc = t / NG;
    const int c  = bc & (NC - 1);
    const int b  = bc >> 6;
    const int4 c4 = reinterpret_cast<const int4*>(cam)[g];
    const int4 u4 = reinterpret_cast<const int4*>(u)[g];
    const int4 v4 = reinterpret_cast<const int4*>(v)[g];
    const int4 w4 = reinterpret_cast<const int4*>(valid)[g];
    const float* fb = feat + (size_t)b * (NCAM * CHW) + (size_t)c * HW;
    float4 o;
    o.x = w4.x ? fb[c4.x * CHW + v4.x * NW + u4.x] : 0.0f;
    o.y = w4.y ? fb[c4.y * CHW + v4.y * NW + u4.y] : 0.0f;
    o.z = w4.z ? fb[c4.z * CHW + v4.z * NW + u4.z] : 0.0f;
    o.w = w4.w ? fb[c4.w * CHW + v4.w * NW + u4.w] : 0.0f;
    reinterpret_cast<float4*>(out)[t] = o;
}

extern "C" void kernel_launch(void* const* d_in, const int* in_sizes, int n_in,
                              void* d_out, int out_size, void* d_ws, size_t ws_size,
                              hipStream_t stream) {
    const float* feat  = (const float*)d_in[0];
    const int*   cam   = (const int*)d_in[1];
    const int*   u     = (const int*)d_in[2];
    const int*   v     = (const int*)d_in[3];
    const int*   valid = (const int*)d_in[4];
    float* out = (float*)d_out;

    if (ws_size >= WS_NEEDED) {
        unsigned short* wst = (unsigned short*)d_ws;
        transpose_kernel<<<NB * NCAM * (HW / 64), 256, 0, stream>>>(feat, wst);
        gather_cl_kernel<<<GBLOCKS, 256, 0, stream>>>(wst, cam, u, v, valid, out);
    } else {
        const int total = NB * NC * (NVOX / 4);
        gather_direct_kernel<<<total / 256, 256, 0, stream>>>(feat, cam, u, v, valid, out);
    }
}